// Round 4
// baseline (407.393 us; speedup 1.0000x reference)
//
#include <hip/hip_runtime.h>

typedef _Float16 f16x8 __attribute__((ext_vector_type(8)));
typedef _Float16 f16x4 __attribute__((ext_vector_type(4)));
typedef float    f32x4 __attribute__((ext_vector_type(4)));

#define GAMMA_F 0.00390625f

// ---------------------------------------------------------------------------
// prep: fp32 -> fp16 row conversion + row sum-of-squares (for x and sv)
// ---------------------------------------------------------------------------
__global__ __launch_bounds__(256) void prep_rows_kernel(
    const float* __restrict__ src, _Float16* __restrict__ dst,
    float* __restrict__ sq, int nrows)
{
    int lane = threadIdx.x & 63, w = threadIdx.x >> 6;
    int row = blockIdx.x * 4 + w;
    if (row >= nrows) return;
    float4 v = ((const float4*)(src + (size_t)row * 256))[lane];
    f16x4 h;
    h[0] = (_Float16)v.x; h[1] = (_Float16)v.y;
    h[2] = (_Float16)v.z; h[3] = (_Float16)v.w;
    *((f16x4*)(dst + (size_t)row * 256) + lane) = h;
    float ss = v.x*v.x + v.y*v.y + v.z*v.z + v.w*v.w;
#pragma unroll
    for (int off = 32; off; off >>= 1) ss += __shfl_down(ss, off);
    if (lane == 0) sq[row] = ss;
}

__global__ __launch_bounds__(256) void cvt_kernel(
    const float* __restrict__ src, _Float16* __restrict__ dst, int n4)
{
    int i = blockIdx.x * 256 + threadIdx.x;
    if (i < n4) {
        float4 v = ((const float4*)src)[i];
        f16x4 h;
        h[0] = (_Float16)v.x; h[1] = (_Float16)v.y;
        h[2] = (_Float16)v.z; h[3] = (_Float16)v.w;
        ((f16x4*)dst)[i] = h;
    }
}

// ---------------------------------------------------------------------------
// 256x256-tile 8-phase GEMM: C[m][n] = epi( sum_k A[m][k]*B[n][k] )
// 8 waves (2M x 4N), BK=64, 2 K-tiles per iteration, dbuf LDS 128 KiB,
// counted vmcnt(4) at phases 4/8, setprio around MFMA clusters,
// st-16x32-style XOR swizzle (pre-swizzled global src, swizzled ds_read).
// NOTE: no sched_barrier anywhere — ds_reads are compiler-visible loads, the
// compiler emits its own fine-grained lgkmcnt; walls were the m141 regression.
//   MODE 0: C = exp(-g*(e0[m] + e1[n] - 2*acc))
//   MODE 1: C = relu(acc + e0[n])
// ---------------------------------------------------------------------------
#define SBAR()  __builtin_amdgcn_s_barrier()
#define LGKM0() asm volatile("s_waitcnt lgkmcnt(0)" ::: "memory")

#define STAGE(gbase, ldsbase, half, kt) do {                                   \
    const _Float16* _g = (gbase) + (size_t)(half) * (128 * K) + (kt) * 64;     \
    __builtin_amdgcn_global_load_lds(                                          \
        (const __attribute__((address_space(1))) void*)_g,                     \
        (__attribute__((address_space(3))) void*)&lds[(ldsbase) + (half)*1024 + t],       \
        16, 0, 0);                                                             \
    __builtin_amdgcn_global_load_lds(                                          \
        (const __attribute__((address_space(1))) void*)(_g + (size_t)64 * K),  \
        (__attribute__((address_space(3))) void*)&lds[(ldsbase) + (half)*1024 + 512 + t], \
        16, 0, 0);                                                             \
} while (0)

#define READ_A(s, mh) do {                                                     \
    _Pragma("unroll") for (int ks = 0; ks < 2; ++ks)                           \
    _Pragma("unroll") for (int mi = 0; mi < 4; ++mi)                           \
        afr[ks][mi] = lds[(s)*2048 +                                           \
            (wr*128 + (mh)*64 + mi*16 + lrow)*8 + ((ks*4+kq) ^ (lrow&7))];     \
} while (0)

#define READ_B(s, nh) do {                                                     \
    _Pragma("unroll") for (int ks = 0; ks < 2; ++ks)                           \
    _Pragma("unroll") for (int nb = 0; nb < 2; ++nb)                           \
        bfr[ks][(nh)*2+nb] = lds[4096 + (s)*2048 +                             \
            (wc*64 + (nh)*32 + nb*16 + lrow)*8 + ((ks*4+kq) ^ (lrow&7))];      \
} while (0)

#define MFMA16(mh, nh) do {                                                    \
    __builtin_amdgcn_s_setprio(1);                                             \
    _Pragma("unroll") for (int mi = 0; mi < 4; ++mi)                           \
    _Pragma("unroll") for (int nb = 0; nb < 2; ++nb)                           \
    _Pragma("unroll") for (int ks = 0; ks < 2; ++ks)                           \
        acc[(mh)*4+mi][(nh)*2+nb] = __builtin_amdgcn_mfma_f32_16x16x32_f16(    \
            afr[ks][mi], bfr[ks][(nh)*2+nb], acc[(mh)*4+mi][(nh)*2+nb], 0,0,0);\
    __builtin_amdgcn_s_setprio(0);                                             \
} while (0)

template <int MODE, int K>
__global__ __launch_bounds__(512, 2) void gemm256_kernel(
    const _Float16* __restrict__ A, const _Float16* __restrict__ B,
    _Float16* __restrict__ C, const float* __restrict__ e0,
    const float* __restrict__ e1)
{
    constexpr int KT = K / 64;
    constexpr int NITER = KT / 2;
    __shared__ f16x8 lds[8192];   // A: [0,4096) = 2 slots x 256r x 8c ; B: [4096,8192)

    const int t    = threadIdx.x;
    const int lane = t & 63, w = t >> 6;
    const int wr   = w >> 2, wc = w & 3;          // 2 x 4 wave grid
    const int lrow = lane & 15, kq = lane >> 4;

    // XCD-aware bijective swizzle (grid % 8 == 0 by construction)
    int bid  = blockIdx.x;
    int cpx  = (int)(gridDim.x >> 3);
    int lbid = (bid & 7) * cpx + (bid >> 3);
    int bm   = lbid >> 2, bn = lbid & 3;          // NB = 1024/256 = 4
    int rowA0 = bm * 256, rowB0 = bn * 256;

    // per-thread staging base (pre-swizzled global source; row&7 == prow&7)
    const int prow = t >> 3;                      // 0..63 (second load adds 64 rows)
    const int cg   = (t & 7) ^ (prow & 7);
    const _Float16* aSB = A + (size_t)(rowA0 + prow) * K + cg * 8;
    const _Float16* bSB = B + (size_t)(rowB0 + prow) * K + cg * 8;

    f32x4 acc[8][4];
#pragma unroll
    for (int i = 0; i < 8; ++i)
#pragma unroll
        for (int j = 0; j < 4; ++j) acc[i][j] = (f32x4){0.f, 0.f, 0.f, 0.f};

    f16x8 afr[2][4], bfr[2][4];

    // ---- prologue: T0 -> slot0, T1 -> slot1 (16 loads/thread) ----
    STAGE(aSB, 0,    0, 0); STAGE(aSB, 0,    1, 0);
    STAGE(bSB, 4096, 0, 0); STAGE(bSB, 4096, 1, 0);
    STAGE(aSB, 2048, 0, 1); STAGE(aSB, 2048, 1, 1);
    STAGE(bSB, 6144, 0, 1); STAGE(bSB, 6144, 1, 1);
    asm volatile("s_waitcnt vmcnt(8)" ::: "memory");   // T0 landed, T1 in flight
    SBAR();

    for (int j = 0; j < NITER; ++j) {
        const bool last = (j == NITER - 1);
        const int tA = 2 * j + 1;      // this iteration's odd tile (A staged ph1/2)
        const int tN = 2 * j + 2;      // next even tile
        const int tO = 2 * j + 3;      // next odd tile

        // ---- phase 1: tile 2j (slot0), quadrant (m0,n0) ----
        READ_A(0, 0); READ_B(0, 0);
        if (j > 0) STAGE(aSB, 2048, 0, tA);            // (2j+1)-A0 -> s1
        SBAR(); LGKM0();
        MFMA16(0, 0);
        SBAR();
        // ---- phase 2: (m0,n1) ----
        READ_B(0, 1);
        if (j > 0) STAGE(aSB, 2048, 1, tA);            // (2j+1)-A1
        SBAR(); LGKM0();
        MFMA16(0, 1);
        SBAR();
        // ---- phase 3: (m1,n0) ----
        READ_A(0, 1);
        if (!last) STAGE(bSB, 4096, 0, tN);            // (2j+2)-B0 -> s0
        SBAR(); LGKM0();
        MFMA16(1, 0);
        SBAR();
        // ---- phase 4: (m1,n1) + counted vmcnt ----
        if (!last) {
            STAGE(bSB, 4096, 1, tN);                   // (2j+2)-B1
            asm volatile("s_waitcnt vmcnt(4)" ::: "memory");
        } else {
            asm volatile("s_waitcnt vmcnt(0)" ::: "memory");
        }
        SBAR(); LGKM0();
        MFMA16(1, 1);
        SBAR();
        // ---- phase 5: tile 2j+1 (slot1), (m0,n0) ----
        READ_A(1, 0); READ_B(1, 0);
        if (!last) STAGE(aSB, 0, 0, tN);               // (2j+2)-A0 -> s0
        SBAR(); LGKM0();
        MFMA16(0, 0);
        SBAR();
        // ---- phase 6: (m0,n1) ----
        READ_B(1, 1);
        if (!last) STAGE(aSB, 0, 1, tN);               // (2j+2)-A1
        SBAR(); LGKM0();
        MFMA16(0, 1);
        SBAR();
        // ---- phase 7: (m1,n0) ----
        READ_A(1, 1);
        if (!last) STAGE(bSB, 6144, 0, tO);            // (2j+3)-B0 -> s1
        SBAR(); LGKM0();
        MFMA16(1, 0);
        SBAR();
        // ---- phase 8: (m1,n1) + counted vmcnt ----
        if (!last) {
            STAGE(bSB, 6144, 1, tO);                   // (2j+3)-B1
            asm volatile("s_waitcnt vmcnt(4)" ::: "memory");
        }
        SBAR(); LGKM0();
        MFMA16(1, 1);
        SBAR();
    }

    // ---- epilogue ----
    int gr0 = rowA0 + wr * 128;
    int gc0 = rowB0 + wc * 64;
    float ecol[4];
#pragma unroll
    for (int ni = 0; ni < 4; ++ni)
        ecol[ni] = (MODE == 0) ? e1[gc0 + ni * 16 + lrow]
                               : e0[gc0 + ni * 16 + lrow];
#pragma unroll
    for (int mi = 0; mi < 8; ++mi) {
#pragma unroll
        for (int jj = 0; jj < 4; ++jj) {
            int row = gr0 + mi * 16 + kq * 4 + jj;
            float xr = (MODE == 0) ? e0[row] : 0.f;
            size_t base = (size_t)row * 1024 + gc0 + lrow;
#pragma unroll
            for (int ni = 0; ni < 4; ++ni) {
                float v = acc[mi][ni][jj];
                if (MODE == 0) {
                    v = __expf(-GAMMA_F * (xr + ecol[ni] - 2.f * v));
                } else {
                    v += ecol[ni];
                    v = fmaxf(v, 0.f);
                }
                C[base + (size_t)ni * 16] = (_Float16)v;
            }
        }
    }
}

// ---------------------------------------------------------------------------
// head: out[b][o] = sum_s h2[b][s]*Wh[o][s] + bh[o], o in {0,1}
// ---------------------------------------------------------------------------
__global__ __launch_bounds__(256) void head_kernel(
    const _Float16* __restrict__ h2, const float* __restrict__ Wh,
    const float* __restrict__ bh, float* __restrict__ out)
{
    int lane = threadIdx.x & 63, w = threadIdx.x >> 6;
    int row = blockIdx.x * 4 + w;
    const _Float16* hp = h2 + (size_t)row * 1024;
    float s0 = 0.f, s1 = 0.f;
#pragma unroll
    for (int i = 0; i < 2; ++i) {
        int base = (i * 64 + lane) * 8;
        f16x8 hv = *(const f16x8*)(hp + base);
#pragma unroll
        for (int j = 0; j < 8; ++j) {
            float hj = (float)hv[j];
            s0 = fmaf(hj, Wh[base + j], s0);
            s1 = fmaf(hj, Wh[1024 + base + j], s1);
        }
    }
#pragma unroll
    for (int off = 32; off; off >>= 1) {
        s0 += __shfl_down(s0, off);
        s1 += __shfl_down(s1, off);
    }
    if (lane == 0) {
        out[(size_t)row * 2 + 0] = s0 + bh[0];
        out[(size_t)row * 2 + 1] = s1 + bh[1];
    }
}

// ---------------------------------------------------------------------------
extern "C" void kernel_launch(void* const* d_in, const int* in_sizes, int n_in,
                              void* d_out, int out_size, void* d_ws, size_t ws_size,
                              hipStream_t stream)
{
    const float* x  = (const float*)d_in[0];
    const float* sv = (const float*)d_in[1];
    const float* W1 = (const float*)d_in[2];
    const float* b1 = (const float*)d_in[3];
    const float* W2 = (const float*)d_in[4];
    const float* b2 = (const float*)d_in[5];
    const float* Wh = (const float*)d_in[6];
    const float* bh = (const float*)d_in[7];
    float* out = (float*)d_out;
    char* ws = (char*)d_ws;

    // ---- persistent region (~4.6 MB) ----
    constexpr size_t OFF_SV = 0;
    constexpr size_t OFF_W1 = OFF_SV + 524288;
    constexpr size_t OFF_W2 = OFF_W1 + 2097152;
    constexpr size_t OFF_S2 = OFF_W2 + 2097152;
    constexpr size_t PERSIST = OFF_S2 + 4096;

    _Float16* svf = (_Float16*)(ws + OFF_SV);
    _Float16* w1f = (_Float16*)(ws + OFF_W1);
    _Float16* w2f = (_Float16*)(ws + OFF_W2);
    float*    s2v = (float*)(ws + OFF_S2);

    // ---- adaptive batch chunking ----
    int Bc = 65536;
    while (Bc > 256 && PERSIST + (size_t)Bc * 4100ULL > ws_size) Bc >>= 1;

    char* chunk_base = ws + PERSIST;
    _Float16* kb  = (_Float16*)chunk_base;                        // Bc x 1024 fp16
    _Float16* h1b = (_Float16*)(chunk_base + (size_t)Bc * 2048);  // Bc x 1024 fp16
    _Float16* xf  = h1b;                                          // overlapped (dies before h1 written)
    float*    x2v = (float*)(chunk_base + (size_t)Bc * 4096);

    prep_rows_kernel<<<1024 / 4, 256, 0, stream>>>(sv, svf, s2v, 1024);
    cvt_kernel<<<1024, 256, 0, stream>>>(W1, w1f, 262144);
    cvt_kernel<<<1024, 256, 0, stream>>>(W2, w2f, 262144);

    int nchunks = 65536 / Bc;
    int ggrid   = (Bc / 256) * 4;
    for (int c = 0; c < nchunks; ++c) {
        const float* xc = x + (size_t)c * Bc * 256;
        prep_rows_kernel<<<Bc / 4, 256, 0, stream>>>(xc, xf, x2v, Bc);
        gemm256_kernel<0, 256><<<ggrid, 512, 0, stream>>>(xf, svf, kb, x2v, s2v);
        gemm256_kernel<1, 1024><<<ggrid, 512, 0, stream>>>(kb, w1f, h1b, b1, nullptr);
        gemm256_kernel<1, 1024><<<ggrid, 512, 0, stream>>>(h1b, w2f, kb, b2, nullptr);
        head_kernel<<<Bc / 4, 256, 0, stream>>>(kb, Wh, bh, out + (size_t)c * Bc * 2);
    }
}

// Round 5
// 406.494 us; speedup vs baseline: 1.0022x; 1.0022x over previous
//
#include <hip/hip_runtime.h>

typedef _Float16 f16x8 __attribute__((ext_vector_type(8)));
typedef _Float16 f16x4 __attribute__((ext_vector_type(4)));
typedef float    f32x4 __attribute__((ext_vector_type(4)));

#define GAMMA_F 0.00390625f

// ---------------------------------------------------------------------------
// prep: fp32 -> fp16 row conversion + row sum-of-squares (for x and sv)
// ---------------------------------------------------------------------------
__global__ __launch_bounds__(256) void prep_rows_kernel(
    const float* __restrict__ src, _Float16* __restrict__ dst,
    float* __restrict__ sq, int nrows)
{
    int lane = threadIdx.x & 63, w = threadIdx.x >> 6;
    int row = blockIdx.x * 4 + w;
    if (row >= nrows) return;
    float4 v = ((const float4*)(src + (size_t)row * 256))[lane];
    f16x4 h;
    h[0] = (_Float16)v.x; h[1] = (_Float16)v.y;
    h[2] = (_Float16)v.z; h[3] = (_Float16)v.w;
    *((f16x4*)(dst + (size_t)row * 256) + lane) = h;
    float ss = v.x*v.x + v.y*v.y + v.z*v.z + v.w*v.w;
#pragma unroll
    for (int off = 32; off; off >>= 1) ss += __shfl_down(ss, off);
    if (lane == 0) sq[row] = ss;
}

__global__ __launch_bounds__(256) void cvt_kernel(
    const float* __restrict__ src, _Float16* __restrict__ dst, int n4)
{
    int i = blockIdx.x * 256 + threadIdx.x;
    if (i < n4) {
        float4 v = ((const float4*)src)[i];
        f16x4 h;
        h[0] = (_Float16)v.x; h[1] = (_Float16)v.y;
        h[2] = (_Float16)v.z; h[3] = (_Float16)v.w;
        ((f16x4*)dst)[i] = h;
    }
}

// ---------------------------------------------------------------------------
// 256x256-tile 8-phase GEMM: C[m][n] = epi( sum_k A[m][k]*B[n][k] )
// 8 waves (2M x 4N), BK=64, 2 K-tiles per iteration, dbuf LDS 128 KiB,
// counted vmcnt(4) at phases 4/8, setprio around MFMA clusters,
// st-16x32-style XOR swizzle (pre-swizzled global src, swizzled ds_read).
// __launch_bounds__(512, 1): LDS already pins 1 block/CU (2 waves/EU); a
// tighter reg bound (512,2 -> 128 VGPR cap) caused ~90 regs of scratch spill
// (r4: VGPR_Count=128, WRITE_SIZE +37MB vs ideal, MfmaUtil stuck at 33%).
//   MODE 0: C = exp(-g*(e0[m] + e1[n] - 2*acc))
//   MODE 1: C = relu(acc + e0[n])
// ---------------------------------------------------------------------------
#define SBAR()  __builtin_amdgcn_s_barrier()
#define LGKM0() asm volatile("s_waitcnt lgkmcnt(0)" ::: "memory")

#define STAGE(gbase, ldsbase, half, kt) do {                                   \
    const _Float16* _g = (gbase) + (size_t)(half) * (128 * K) + (kt) * 64;     \
    __builtin_amdgcn_global_load_lds(                                          \
        (const __attribute__((address_space(1))) void*)_g,                     \
        (__attribute__((address_space(3))) void*)&lds[(ldsbase) + (half)*1024 + t],       \
        16, 0, 0);                                                             \
    __builtin_amdgcn_global_load_lds(                                          \
        (const __attribute__((address_space(1))) void*)(_g + (size_t)64 * K),  \
        (__attribute__((address_space(3))) void*)&lds[(ldsbase) + (half)*1024 + 512 + t], \
        16, 0, 0);                                                             \
} while (0)

#define READ_A(s, mh) do {                                                     \
    _Pragma("unroll") for (int ks = 0; ks < 2; ++ks)                           \
    _Pragma("unroll") for (int mi = 0; mi < 4; ++mi)                           \
        afr[ks][mi] = lds[(s)*2048 +                                           \
            (wr*128 + (mh)*64 + mi*16 + lrow)*8 + ((ks*4+kq) ^ (lrow&7))];     \
} while (0)

#define READ_B(s, nh) do {                                                     \
    _Pragma("unroll") for (int ks = 0; ks < 2; ++ks)                           \
    _Pragma("unroll") for (int nb = 0; nb < 2; ++nb)                           \
        bfr[ks][(nh)*2+nb] = lds[4096 + (s)*2048 +                             \
            (wc*64 + (nh)*32 + nb*16 + lrow)*8 + ((ks*4+kq) ^ (lrow&7))];      \
} while (0)

#define MFMA16(mh, nh) do {                                                    \
    __builtin_amdgcn_s_setprio(1);                                             \
    _Pragma("unroll") for (int mi = 0; mi < 4; ++mi)                           \
    _Pragma("unroll") for (int nb = 0; nb < 2; ++nb)                           \
    _Pragma("unroll") for (int ks = 0; ks < 2; ++ks)                           \
        acc[(mh)*4+mi][(nh)*2+nb] = __builtin_amdgcn_mfma_f32_16x16x32_f16(    \
            afr[ks][mi], bfr[ks][(nh)*2+nb], acc[(mh)*4+mi][(nh)*2+nb], 0,0,0);\
    __builtin_amdgcn_s_setprio(0);                                             \
} while (0)

template <int MODE, int K>
__global__ __launch_bounds__(512, 1) void gemm256_kernel(
    const _Float16* __restrict__ A, const _Float16* __restrict__ B,
    _Float16* __restrict__ C, const float* __restrict__ e0,
    const float* __restrict__ e1)
{
    constexpr int KT = K / 64;
    constexpr int NITER = KT / 2;
    __shared__ f16x8 lds[8192];   // A: [0,4096) = 2 slots x 256r x 8c ; B: [4096,8192)

    const int t    = threadIdx.x;
    const int lane = t & 63, w = t >> 6;
    const int wr   = w >> 2, wc = w & 3;          // 2 x 4 wave grid
    const int lrow = lane & 15, kq = lane >> 4;

    // XCD-aware bijective swizzle (grid % 8 == 0 by construction)
    int bid  = blockIdx.x;
    int cpx  = (int)(gridDim.x >> 3);
    int lbid = (bid & 7) * cpx + (bid >> 3);
    int bm   = lbid >> 2, bn = lbid & 3;          // NB = 1024/256 = 4
    int rowA0 = bm * 256, rowB0 = bn * 256;

    // per-thread staging base (pre-swizzled global source; row&7 == prow&7)
    const int prow = t >> 3;                      // 0..63 (second load adds 64 rows)
    const int cg   = (t & 7) ^ (prow & 7);
    const _Float16* aSB = A + (size_t)(rowA0 + prow) * K + cg * 8;
    const _Float16* bSB = B + (size_t)(rowB0 + prow) * K + cg * 8;

    f32x4 acc[8][4];
#pragma unroll
    for (int i = 0; i < 8; ++i)
#pragma unroll
        for (int j = 0; j < 4; ++j) acc[i][j] = (f32x4){0.f, 0.f, 0.f, 0.f};

    f16x8 afr[2][4], bfr[2][4];

    // ---- prologue: T0 -> slot0, T1 -> slot1 (16 loads/thread) ----
    STAGE(aSB, 0,    0, 0); STAGE(aSB, 0,    1, 0);
    STAGE(bSB, 4096, 0, 0); STAGE(bSB, 4096, 1, 0);
    STAGE(aSB, 2048, 0, 1); STAGE(aSB, 2048, 1, 1);
    STAGE(bSB, 6144, 0, 1); STAGE(bSB, 6144, 1, 1);
    asm volatile("s_waitcnt vmcnt(8)" ::: "memory");   // T0 landed, T1 in flight
    SBAR();

    for (int j = 0; j < NITER; ++j) {
        const bool last = (j == NITER - 1);
        const int tA = 2 * j + 1;      // this iteration's odd tile (A staged ph1/2)
        const int tN = 2 * j + 2;      // next even tile
        const int tO = 2 * j + 3;      // next odd tile

        // ---- phase 1: tile 2j (slot0), quadrant (m0,n0) ----
        READ_A(0, 0); READ_B(0, 0);
        if (j > 0) STAGE(aSB, 2048, 0, tA);            // (2j+1)-A0 -> s1
        SBAR(); LGKM0();
        MFMA16(0, 0);
        SBAR();
        // ---- phase 2: (m0,n1) ----
        READ_B(0, 1);
        if (j > 0) STAGE(aSB, 2048, 1, tA);            // (2j+1)-A1
        SBAR(); LGKM0();
        MFMA16(0, 1);
        SBAR();
        // ---- phase 3: (m1,n0) ----
        READ_A(0, 1);
        if (!last) STAGE(bSB, 4096, 0, tN);            // (2j+2)-B0 -> s0
        SBAR(); LGKM0();
        MFMA16(1, 0);
        SBAR();
        // ---- phase 4: (m1,n1) + counted vmcnt ----
        if (!last) {
            STAGE(bSB, 4096, 1, tN);                   // (2j+2)-B1
            asm volatile("s_waitcnt vmcnt(4)" ::: "memory");
        } else {
            asm volatile("s_waitcnt vmcnt(0)" ::: "memory");
        }
        SBAR(); LGKM0();
        MFMA16(1, 1);
        SBAR();
        // ---- phase 5: tile 2j+1 (slot1), (m0,n0) ----
        READ_A(1, 0); READ_B(1, 0);
        if (!last) STAGE(aSB, 0, 0, tN);               // (2j+2)-A0 -> s0
        SBAR(); LGKM0();
        MFMA16(0, 0);
        SBAR();
        // ---- phase 6: (m0,n1) ----
        READ_B(1, 1);
        if (!last) STAGE(aSB, 0, 1, tN);               // (2j+2)-A1
        SBAR(); LGKM0();
        MFMA16(0, 1);
        SBAR();
        // ---- phase 7: (m1,n0) ----
        READ_A(1, 1);
        if (!last) STAGE(bSB, 6144, 0, tO);            // (2j+3)-B0 -> s1
        SBAR(); LGKM0();
        MFMA16(1, 0);
        SBAR();
        // ---- phase 8: (m1,n1) + counted vmcnt ----
        if (!last) {
            STAGE(bSB, 6144, 1, tO);                   // (2j+3)-B1
            asm volatile("s_waitcnt vmcnt(4)" ::: "memory");
        }
        SBAR(); LGKM0();
        MFMA16(1, 1);
        SBAR();
    }

    // ---- epilogue ----
    int gr0 = rowA0 + wr * 128;
    int gc0 = rowB0 + wc * 64;
    float ecol[4];
#pragma unroll
    for (int ni = 0; ni < 4; ++ni)
        ecol[ni] = (MODE == 0) ? e1[gc0 + ni * 16 + lrow]
                               : e0[gc0 + ni * 16 + lrow];
#pragma unroll
    for (int mi = 0; mi < 8; ++mi) {
#pragma unroll
        for (int jj = 0; jj < 4; ++jj) {
            int row = gr0 + mi * 16 + kq * 4 + jj;
            float xr = (MODE == 0) ? e0[row] : 0.f;
            size_t base = (size_t)row * 1024 + gc0 + lrow;
#pragma unroll
            for (int ni = 0; ni < 4; ++ni) {
                float v = acc[mi][ni][jj];
                if (MODE == 0) {
                    v = __expf(-GAMMA_F * (xr + ecol[ni] - 2.f * v));
                } else {
                    v += ecol[ni];
                    v = fmaxf(v, 0.f);
                }
                C[base + (size_t)ni * 16] = (_Float16)v;
            }
        }
    }
}

// ---------------------------------------------------------------------------
// head: out[b][o] = sum_s h2[b][s]*Wh[o][s] + bh[o], o in {0,1}
// ---------------------------------------------------------------------------
__global__ __launch_bounds__(256) void head_kernel(
    const _Float16* __restrict__ h2, const float* __restrict__ Wh,
    const float* __restrict__ bh, float* __restrict__ out)
{
    int lane = threadIdx.x & 63, w = threadIdx.x >> 6;
    int row = blockIdx.x * 4 + w;
    const _Float16* hp = h2 + (size_t)row * 1024;
    float s0 = 0.f, s1 = 0.f;
#pragma unroll
    for (int i = 0; i < 2; ++i) {
        int base = (i * 64 + lane) * 8;
        f16x8 hv = *(const f16x8*)(hp + base);
#pragma unroll
        for (int j = 0; j < 8; ++j) {
            float hj = (float)hv[j];
            s0 = fmaf(hj, Wh[base + j], s0);
            s1 = fmaf(hj, Wh[1024 + base + j], s1);
        }
    }
#pragma unroll
    for (int off = 32; off; off >>= 1) {
        s0 += __shfl_down(s0, off);
        s1 += __shfl_down(s1, off);
    }
    if (lane == 0) {
        out[(size_t)row * 2 + 0] = s0 + bh[0];
        out[(size_t)row * 2 + 1] = s1 + bh[1];
    }
}

// ---------------------------------------------------------------------------
extern "C" void kernel_launch(void* const* d_in, const int* in_sizes, int n_in,
                              void* d_out, int out_size, void* d_ws, size_t ws_size,
                              hipStream_t stream)
{
    const float* x  = (const float*)d_in[0];
    const float* sv = (const float*)d_in[1];
    const float* W1 = (const float*)d_in[2];
    const float* b1 = (const float*)d_in[3];
    const float* W2 = (const float*)d_in[4];
    const float* b2 = (const float*)d_in[5];
    const float* Wh = (const float*)d_in[6];
    const float* bh = (const float*)d_in[7];
    float* out = (float*)d_out;
    char* ws = (char*)d_ws;

    // ---- persistent region (~4.6 MB) ----
    constexpr size_t OFF_SV = 0;
    constexpr size_t OFF_W1 = OFF_SV + 524288;
    constexpr size_t OFF_W2 = OFF_W1 + 2097152;
    constexpr size_t OFF_S2 = OFF_W2 + 2097152;
    constexpr size_t PERSIST = OFF_S2 + 4096;

    _Float16* svf = (_Float16*)(ws + OFF_SV);
    _Float16* w1f = (_Float16*)(ws + OFF_W1);
    _Float16* w2f = (_Float16*)(ws + OFF_W2);
    float*    s2v = (float*)(ws + OFF_S2);

    // ---- adaptive batch chunking ----
    int Bc = 65536;
    while (Bc > 256 && PERSIST + (size_t)Bc * 4100ULL > ws_size) Bc >>= 1;

    char* chunk_base = ws + PERSIST;
    _Float16* kb  = (_Float16*)chunk_base;                        // Bc x 1024 fp16
    _Float16* h1b = (_Float16*)(chunk_base + (size_t)Bc * 2048);  // Bc x 1024 fp16
    _Float16* xf  = h1b;                                          // overlapped (dies before h1 written)
    float*    x2v = (float*)(chunk_base + (size_t)Bc * 4096);

    prep_rows_kernel<<<1024 / 4, 256, 0, stream>>>(sv, svf, s2v, 1024);
    cvt_kernel<<<1024, 256, 0, stream>>>(W1, w1f, 262144);
    cvt_kernel<<<1024, 256, 0, stream>>>(W2, w2f, 262144);

    int nchunks = 65536 / Bc;
    int ggrid   = (Bc / 256) * 4;
    for (int c = 0; c < nchunks; ++c) {
        const float* xc = x + (size_t)c * Bc * 256;
        prep_rows_kernel<<<Bc / 4, 256, 0, stream>>>(xc, xf, x2v, Bc);
        gemm256_kernel<0, 256><<<ggrid, 512, 0, stream>>>(xf, svf, kb, x2v, s2v);
        gemm256_kernel<1, 1024><<<ggrid, 512, 0, stream>>>(kb, w1f, h1b, b1, nullptr);
        gemm256_kernel<1, 1024><<<ggrid, 512, 0, stream>>>(h1b, w2f, kb, b2, nullptr);
        head_kernel<<<Bc / 4, 256, 0, stream>>>(kb, Wh, bh, out + (size_t)c * Bc * 2);
    }
}

// Round 6
// 406.376 us; speedup vs baseline: 1.0025x; 1.0003x over previous
//
#include <hip/hip_runtime.h>

typedef _Float16 f16x8 __attribute__((ext_vector_type(8)));
typedef _Float16 f16x4 __attribute__((ext_vector_type(4)));
typedef float    f32x4 __attribute__((ext_vector_type(4)));

#define GAMMA_F 0.00390625f

// ---------------------------------------------------------------------------
// prep: fp32 -> fp16 row conversion + row sum-of-squares (for x and sv)
// ---------------------------------------------------------------------------
__global__ __launch_bounds__(256) void prep_rows_kernel(
    const float* __restrict__ src, _Float16* __restrict__ dst,
    float* __restrict__ sq, int nrows)
{
    int lane = threadIdx.x & 63, w = threadIdx.x >> 6;
    int row = blockIdx.x * 4 + w;
    if (row >= nrows) return;
    float4 v = ((const float4*)(src + (size_t)row * 256))[lane];
    f16x4 h;
    h[0] = (_Float16)v.x; h[1] = (_Float16)v.y;
    h[2] = (_Float16)v.z; h[3] = (_Float16)v.w;
    *((f16x4*)(dst + (size_t)row * 256) + lane) = h;
    float ss = v.x*v.x + v.y*v.y + v.z*v.z + v.w*v.w;
#pragma unroll
    for (int off = 32; off; off >>= 1) ss += __shfl_down(ss, off);
    if (lane == 0) sq[row] = ss;
}

__global__ __launch_bounds__(256) void cvt_kernel(
    const float* __restrict__ src, _Float16* __restrict__ dst, int n4)
{
    int i = blockIdx.x * 256 + threadIdx.x;
    if (i < n4) {
        float4 v = ((const float4*)src)[i];
        f16x4 h;
        h[0] = (_Float16)v.x; h[1] = (_Float16)v.y;
        h[2] = (_Float16)v.z; h[3] = (_Float16)v.w;
        ((f16x4*)dst)[i] = h;
    }
}

// ---------------------------------------------------------------------------
// 256x256-tile 8-phase GEMM: C[m][n] = epi( sum_k A[m][k]*B[n][k] )
// 8 waves (2M x 4N), BK=64, 2 K-tiles per iteration, dbuf LDS 128 KiB,
// counted vmcnt(4) at phases 4/8, setprio around MFMA clusters,
// st-16x32-style XOR swizzle (pre-swizzled global src, swizzled ds_read).
// NO explicit lgkmcnt before MFMA: the monolithic asm lgkmcnt(0) serialized
// ~300-430 cyc of LDS-read time against 516 cyc of MFMA time EVERY phase
// (r5: phase wall 1500 cyc, MfmaUtil 34% == 516/1500). Compiler-inserted
// fine-grained lgkmcnt(N) per fragment use overlaps LDS reads with MFMA.
//   MODE 0: C = exp(-g*(e0[m] + e1[n] - 2*acc))
//   MODE 1: C = relu(acc + e0[n])
// ---------------------------------------------------------------------------
#define SBAR()  __builtin_amdgcn_s_barrier()

#define STAGE(gbase, ldsbase, half, kt) do {                                   \
    const _Float16* _g = (gbase) + (size_t)(half) * (128 * K) + (kt) * 64;     \
    __builtin_amdgcn_global_load_lds(                                          \
        (const __attribute__((address_space(1))) void*)_g,                     \
        (__attribute__((address_space(3))) void*)&lds[(ldsbase) + (half)*1024 + t],       \
        16, 0, 0);                                                             \
    __builtin_amdgcn_global_load_lds(                                          \
        (const __attribute__((address_space(1))) void*)(_g + (size_t)64 * K),  \
        (__attribute__((address_space(3))) void*)&lds[(ldsbase) + (half)*1024 + 512 + t], \
        16, 0, 0);                                                             \
} while (0)

#define READ_A(s, mh) do {                                                     \
    _Pragma("unroll") for (int ks = 0; ks < 2; ++ks)                           \
    _Pragma("unroll") for (int mi = 0; mi < 4; ++mi)                           \
        afr[ks][mi] = lds[(s)*2048 +                                           \
            (wr*128 + (mh)*64 + mi*16 + lrow)*8 + ((ks*4+kq) ^ (lrow&7))];     \
} while (0)

#define READ_B(s, nh) do {                                                     \
    _Pragma("unroll") for (int ks = 0; ks < 2; ++ks)                           \
    _Pragma("unroll") for (int nb = 0; nb < 2; ++nb)                           \
        bfr[ks][(nh)*2+nb] = lds[4096 + (s)*2048 +                             \
            (wc*64 + (nh)*32 + nb*16 + lrow)*8 + ((ks*4+kq) ^ (lrow&7))];      \
} while (0)

#define MFMA16(mh, nh) do {                                                    \
    __builtin_amdgcn_s_setprio(1);                                             \
    _Pragma("unroll") for (int mi = 0; mi < 4; ++mi)                           \
    _Pragma("unroll") for (int nb = 0; nb < 2; ++nb)                           \
    _Pragma("unroll") for (int ks = 0; ks < 2; ++ks)                           \
        acc[(mh)*4+mi][(nh)*2+nb] = __builtin_amdgcn_mfma_f32_16x16x32_f16(    \
            afr[ks][mi], bfr[ks][(nh)*2+nb], acc[(mh)*4+mi][(nh)*2+nb], 0,0,0);\
    __builtin_amdgcn_s_setprio(0);                                             \
} while (0)

template <int MODE, int K>
__global__ __launch_bounds__(512, 1) void gemm256_kernel(
    const _Float16* __restrict__ A, const _Float16* __restrict__ B,
    _Float16* __restrict__ C, const float* __restrict__ e0,
    const float* __restrict__ e1)
{
    constexpr int KT = K / 64;
    constexpr int NITER = KT / 2;
    __shared__ f16x8 lds[8192];   // A: [0,4096) = 2 slots x 256r x 8c ; B: [4096,8192)

    const int t    = threadIdx.x;
    const int lane = t & 63, w = t >> 6;
    const int wr   = w >> 2, wc = w & 3;          // 2 x 4 wave grid
    const int lrow = lane & 15, kq = lane >> 4;

    // XCD-aware bijective swizzle (grid % 8 == 0 by construction)
    int bid  = blockIdx.x;
    int cpx  = (int)(gridDim.x >> 3);
    int lbid = (bid & 7) * cpx + (bid >> 3);
    int bm   = lbid >> 2, bn = lbid & 3;          // NB = 1024/256 = 4
    int rowA0 = bm * 256, rowB0 = bn * 256;

    // per-thread staging base (pre-swizzled global source; row&7 == prow&7)
    const int prow = t >> 3;                      // 0..63 (second load adds 64 rows)
    const int cg   = (t & 7) ^ (prow & 7);
    const _Float16* aSB = A + (size_t)(rowA0 + prow) * K + cg * 8;
    const _Float16* bSB = B + (size_t)(rowB0 + prow) * K + cg * 8;

    f32x4 acc[8][4];
#pragma unroll
    for (int i = 0; i < 8; ++i)
#pragma unroll
        for (int j = 0; j < 4; ++j) acc[i][j] = (f32x4){0.f, 0.f, 0.f, 0.f};

    f16x8 afr[2][4], bfr[2][4];

    // ---- prologue: T0 -> slot0, T1 -> slot1 (16 loads/thread) ----
    STAGE(aSB, 0,    0, 0); STAGE(aSB, 0,    1, 0);
    STAGE(bSB, 4096, 0, 0); STAGE(bSB, 4096, 1, 0);
    STAGE(aSB, 2048, 0, 1); STAGE(aSB, 2048, 1, 1);
    STAGE(bSB, 6144, 0, 1); STAGE(bSB, 6144, 1, 1);
    asm volatile("s_waitcnt vmcnt(8)" ::: "memory");   // T0 landed, T1 in flight
    SBAR();

    for (int j = 0; j < NITER; ++j) {
        const bool last = (j == NITER - 1);
        const int tA = 2 * j + 1;      // this iteration's odd tile (A staged ph1/2)
        const int tN = 2 * j + 2;      // next even tile
        const int tO = 2 * j + 3;      // next odd tile

        // ---- phase 1: tile 2j (slot0), quadrant (m0,n0) ----
        READ_A(0, 0); READ_B(0, 0);
        if (j > 0) STAGE(aSB, 2048, 0, tA);            // (2j+1)-A0 -> s1
        SBAR();
        MFMA16(0, 0);
        SBAR();
        // ---- phase 2: (m0,n1) ----
        READ_B(0, 1);
        if (j > 0) STAGE(aSB, 2048, 1, tA);            // (2j+1)-A1
        SBAR();
        MFMA16(0, 1);
        SBAR();
        // ---- phase 3: (m1,n0) ----
        READ_A(0, 1);
        if (!last) STAGE(bSB, 4096, 0, tN);            // (2j+2)-B0 -> s0
        SBAR();
        MFMA16(1, 0);
        SBAR();
        // ---- phase 4: (m1,n1) + counted vmcnt ----
        if (!last) {
            STAGE(bSB, 4096, 1, tN);                   // (2j+2)-B1
            asm volatile("s_waitcnt vmcnt(4)" ::: "memory");
        } else {
            asm volatile("s_waitcnt vmcnt(0)" ::: "memory");
        }
        SBAR();
        MFMA16(1, 1);
        SBAR();
        // ---- phase 5: tile 2j+1 (slot1), (m0,n0) ----
        READ_A(1, 0); READ_B(1, 0);
        if (!last) STAGE(aSB, 0, 0, tN);               // (2j+2)-A0 -> s0
        SBAR();
        MFMA16(0, 0);
        SBAR();
        // ---- phase 6: (m0,n1) ----
        READ_B(1, 1);
        if (!last) STAGE(aSB, 0, 1, tN);               // (2j+2)-A1
        SBAR();
        MFMA16(0, 1);
        SBAR();
        // ---- phase 7: (m1,n0) ----
        READ_A(1, 1);
        if (!last) STAGE(bSB, 6144, 0, tO);            // (2j+3)-B0 -> s1
        SBAR();
        MFMA16(1, 0);
        SBAR();
        // ---- phase 8: (m1,n1) + counted vmcnt ----
        if (!last) {
            STAGE(bSB, 6144, 1, tO);                   // (2j+3)-B1
            asm volatile("s_waitcnt vmcnt(4)" ::: "memory");
        }
        SBAR();
        MFMA16(1, 1);
        SBAR();
    }

    // ---- epilogue ----
    int gr0 = rowA0 + wr * 128;
    int gc0 = rowB0 + wc * 64;
    float ecol[4];
#pragma unroll
    for (int ni = 0; ni < 4; ++ni)
        ecol[ni] = (MODE == 0) ? e1[gc0 + ni * 16 + lrow]
                               : e0[gc0 + ni * 16 + lrow];
#pragma unroll
    for (int mi = 0; mi < 8; ++mi) {
#pragma unroll
        for (int jj = 0; jj < 4; ++jj) {
            int row = gr0 + mi * 16 + kq * 4 + jj;
            float xr = (MODE == 0) ? e0[row] : 0.f;
            size_t base = (size_t)row * 1024 + gc0 + lrow;
#pragma unroll
            for (int ni = 0; ni < 4; ++ni) {
                float v = acc[mi][ni][jj];
                if (MODE == 0) {
                    v = __expf(-GAMMA_F * (xr + ecol[ni] - 2.f * v));
                } else {
                    v += ecol[ni];
                    v = fmaxf(v, 0.f);
                }
                C[base + (size_t)ni * 16] = (_Float16)v;
            }
        }
    }
}

// ---------------------------------------------------------------------------
// head: out[b][o] = sum_s h2[b][s]*Wh[o][s] + bh[o], o in {0,1}
// ---------------------------------------------------------------------------
__global__ __launch_bounds__(256) void head_kernel(
    const _Float16* __restrict__ h2, const float* __restrict__ Wh,
    const float* __restrict__ bh, float* __restrict__ out)
{
    int lane = threadIdx.x & 63, w = threadIdx.x >> 6;
    int row = blockIdx.x * 4 + w;
    const _Float16* hp = h2 + (size_t)row * 1024;
    float s0 = 0.f, s1 = 0.f;
#pragma unroll
    for (int i = 0; i < 2; ++i) {
        int base = (i * 64 + lane) * 8;
        f16x8 hv = *(const f16x8*)(hp + base);
#pragma unroll
        for (int j = 0; j < 8; ++j) {
            float hj = (float)hv[j];
            s0 = fmaf(hj, Wh[base + j], s0);
            s1 = fmaf(hj, Wh[1024 + base + j], s1);
        }
    }
#pragma unroll
    for (int off = 32; off; off >>= 1) {
        s0 += __shfl_down(s0, off);
        s1 += __shfl_down(s1, off);
    }
    if (lane == 0) {
        out[(size_t)row * 2 + 0] = s0 + bh[0];
        out[(size_t)row * 2 + 1] = s1 + bh[1];
    }
}

// ---------------------------------------------------------------------------
extern "C" void kernel_launch(void* const* d_in, const int* in_sizes, int n_in,
                              void* d_out, int out_size, void* d_ws, size_t ws_size,
                              hipStream_t stream)
{
    const float* x  = (const float*)d_in[0];
    const float* sv = (const float*)d_in[1];
    const float* W1 = (const float*)d_in[2];
    const float* b1 = (const float*)d_in[3];
    const float* W2 = (const float*)d_in[4];
    const float* b2 = (const float*)d_in[5];
    const float* Wh = (const float*)d_in[6];
    const float* bh = (const float*)d_in[7];
    float* out = (float*)d_out;
    char* ws = (char*)d_ws;

    // ---- persistent region (~4.6 MB) ----
    constexpr size_t OFF_SV = 0;
    constexpr size_t OFF_W1 = OFF_SV + 524288;
    constexpr size_t OFF_W2 = OFF_W1 + 2097152;
    constexpr size_t OFF_S2 = OFF_W2 + 2097152;
    constexpr size_t PERSIST = OFF_S2 + 4096;

    _Float16* svf = (_Float16*)(ws + OFF_SV);
    _Float16* w1f = (_Float16*)(ws + OFF_W1);
    _Float16* w2f = (_Float16*)(ws + OFF_W2);
    float*    s2v = (float*)(ws + OFF_S2);

    // ---- adaptive batch chunking ----
    int Bc = 65536;
    while (Bc > 256 && PERSIST + (size_t)Bc * 4100ULL > ws_size) Bc >>= 1;

    char* chunk_base = ws + PERSIST;
    _Float16* kb  = (_Float16*)chunk_base;                        // Bc x 1024 fp16
    _Float16* h1b = (_Float16*)(chunk_base + (size_t)Bc * 2048);  // Bc x 1024 fp16
    _Float16* xf  = h1b;                                          // overlapped (dies before h1 written)
    float*    x2v = (float*)(chunk_base + (size_t)Bc * 4096);

    prep_rows_kernel<<<1024 / 4, 256, 0, stream>>>(sv, svf, s2v, 1024);
    cvt_kernel<<<1024, 256, 0, stream>>>(W1, w1f, 262144);
    cvt_kernel<<<1024, 256, 0, stream>>>(W2, w2f, 262144);

    int nchunks = 65536 / Bc;
    int ggrid   = (Bc / 256) * 4;
    for (int c = 0; c < nchunks; ++c) {
        const float* xc = x + (size_t)c * Bc * 256;
        prep_rows_kernel<<<Bc / 4, 256, 0, stream>>>(xc, xf, x2v, Bc);
        gemm256_kernel<0, 256><<<ggrid, 512, 0, stream>>>(xf, svf, kb, x2v, s2v);
        gemm256_kernel<1, 1024><<<ggrid, 512, 0, stream>>>(kb, w1f, h1b, b1, nullptr);
        gemm256_kernel<1, 1024><<<ggrid, 512, 0, stream>>>(h1b, w2f, kb, b2, nullptr);
        head_kernel<<<Bc / 4, 256, 0, stream>>>(kb, Wh, bh, out + (size_t)c * Bc * 2);
    }
}

// Round 7
// 397.961 us; speedup vs baseline: 1.0237x; 1.0211x over previous
//
#include <hip/hip_runtime.h>

typedef _Float16 f16x8 __attribute__((ext_vector_type(8)));
typedef _Float16 f16x4 __attribute__((ext_vector_type(4)));
typedef float    f32x4 __attribute__((ext_vector_type(4)));

#define GAMMA_F 0.00390625f

// ---------------------------------------------------------------------------
// prep: fp32 -> fp16 row conversion + row sum-of-squares (for x and sv)
// ---------------------------------------------------------------------------
__global__ __launch_bounds__(256) void prep_rows_kernel(
    const float* __restrict__ src, _Float16* __restrict__ dst,
    float* __restrict__ sq, int nrows)
{
    int lane = threadIdx.x & 63, w = threadIdx.x >> 6;
    int row = blockIdx.x * 4 + w;
    if (row >= nrows) return;
    float4 v = ((const float4*)(src + (size_t)row * 256))[lane];
    f16x4 h;
    h[0] = (_Float16)v.x; h[1] = (_Float16)v.y;
    h[2] = (_Float16)v.z; h[3] = (_Float16)v.w;
    *((f16x4*)(dst + (size_t)row * 256) + lane) = h;
    float ss = v.x*v.x + v.y*v.y + v.z*v.z + v.w*v.w;
#pragma unroll
    for (int off = 32; off; off >>= 1) ss += __shfl_down(ss, off);
    if (lane == 0) sq[row] = ss;
}

__global__ __launch_bounds__(256) void cvt_kernel(
    const float* __restrict__ src, _Float16* __restrict__ dst, int n4)
{
    int i = blockIdx.x * 256 + threadIdx.x;
    if (i < n4) {
        float4 v = ((const float4*)src)[i];
        f16x4 h;
        h[0] = (_Float16)v.x; h[1] = (_Float16)v.y;
        h[2] = (_Float16)v.z; h[3] = (_Float16)v.w;
        ((f16x4*)dst)[i] = h;
    }
}

// ---------------------------------------------------------------------------
// 256x256-tile 8-phase GEMM. Register-pressure discipline:
//   - acc[8][4] = 128 AGPRs; unified file at 2 waves/SIMD = 256 regs total
//     => arch VGPRs capped at 128 (r3-r6: VGPR_Count=128, WRITE_SIZE +37MB
//     spill signature). All LDS-read addressing hoisted into 4 base byte
//     offsets (ds_read = base + 16-bit imm); staging into 2 advancing
//     pointers. Inner-loop arch demand ~90 regs -> no spill.
//   MODE 0: C = exp(-g*(e0[m] + e1[n] - 2*acc))
//   MODE 1: C = relu(acc + e0[n])
// ---------------------------------------------------------------------------
#define SBAR()  __builtin_amdgcn_s_barrier()
#define AS1 __attribute__((address_space(1)))
#define AS3 __attribute__((address_space(3)))

// one 16B chunk to LDS; dest = compile-time-const region + t*16
#define GLD(gptr, dstoff) __builtin_amdgcn_global_load_lds(                    \
    (const AS1 void*)(gptr), (AS3 void*)(ldsb + (dstoff)), 16, 0, 0)

// stage half-tile (128 rows) of A/B tile at the current pointer into slot
#define STAGE_A(slot, half) do {                                               \
    GLD(aStage + (size_t)(half)*128*K,        (slot)*32768 + (half)*16384 + tb);          \
    GLD(aStage + (size_t)(half)*128*K + 64*K, (slot)*32768 + (half)*16384 + 8192 + tb);   \
} while (0)
#define STAGE_B(slot, half) do {                                               \
    GLD(bStage + (size_t)(half)*128*K,        65536 + (slot)*32768 + (half)*16384 + tb);        \
    GLD(bStage + (size_t)(half)*128*K + 64*K, 65536 + (slot)*32768 + (half)*16384 + 8192 + tb); \
} while (0)

#define READ_A(s, mh) do {                                                     \
    _Pragma("unroll") for (int mi = 0; mi < 4; ++mi) {                         \
        afr[0][mi] = *(const f16x8*)(ldsb + aO0 + (s)*32768 + (mh)*8192 + mi*2048); \
        afr[1][mi] = *(const f16x8*)(ldsb + aO1 + (s)*32768 + (mh)*8192 + mi*2048); \
    } } while (0)

#define READ_B(s, nh) do {                                                     \
    _Pragma("unroll") for (int nb = 0; nb < 2; ++nb) {                         \
        bfr[0][(nh)*2+nb] = *(const f16x8*)(ldsb + bO0 + (s)*32768 + (nh)*4096 + nb*2048); \
        bfr[1][(nh)*2+nb] = *(const f16x8*)(ldsb + bO1 + (s)*32768 + (nh)*4096 + nb*2048); \
    } } while (0)

#define MFMA16(mh, nh) do {                                                    \
    __builtin_amdgcn_s_setprio(1);                                             \
    _Pragma("unroll") for (int mi = 0; mi < 4; ++mi)                           \
    _Pragma("unroll") for (int nb = 0; nb < 2; ++nb)                           \
    _Pragma("unroll") for (int ks = 0; ks < 2; ++ks)                           \
        acc[(mh)*4+mi][(nh)*2+nb] = __builtin_amdgcn_mfma_f32_16x16x32_f16(    \
            afr[ks][mi], bfr[ks][(nh)*2+nb], acc[(mh)*4+mi][(nh)*2+nb], 0,0,0);\
    __builtin_amdgcn_s_setprio(0);                                             \
} while (0)

template <int MODE, int K>
__global__ __launch_bounds__(512, 1) void gemm256_kernel(
    const _Float16* __restrict__ A, const _Float16* __restrict__ B,
    _Float16* __restrict__ C, const float* __restrict__ e0,
    const float* __restrict__ e1)
{
    constexpr int KT = K / 64;
    constexpr int NITER = KT / 2;
    __shared__ f16x8 lds[8192];   // A: bytes [0,65536) = 2 slots; B: [65536,131072)
    char* ldsb = (char*)lds;

    const int t    = threadIdx.x;
    const int tb   = t * 16;
    const int lane = t & 63, w = t >> 6;
    const int wr   = w >> 2, wc = w & 3;          // 2 x 4 wave grid
    const int lrow = lane & 15, kq = lane >> 4;

    // XCD-aware bijective swizzle (grid % 8 == 0 by construction)
    int bid  = blockIdx.x;
    int cpx  = (int)(gridDim.x >> 3);
    int lbid = (bid & 7) * cpx + (bid >> 3);
    int bm   = lbid >> 2, bn = lbid & 3;          // NB = 1024/256 = 4
    int rowA0 = bm * 256, rowB0 = bn * 256;

    // LDS-read base byte offsets (everything else is a compile-time imm)
    const int aO0 = ((wr*128 + lrow)*8 + ( kq      ^ (lrow & 7))) * 16;
    const int aO1 = ((wr*128 + lrow)*8 + ((4 + kq) ^ (lrow & 7))) * 16;
    const int bO0 = 65536 + ((wc*64 + lrow)*8 + ( kq      ^ (lrow & 7))) * 16;
    const int bO1 = 65536 + ((wc*64 + lrow)*8 + ((4 + kq) ^ (lrow & 7))) * 16;

    // staging pointers (pre-swizzled source; advance +64 elems per K-tile)
    const int prow = t >> 3;
    const int cg   = (t & 7) ^ (prow & 7);
    const _Float16* aStage = A + (size_t)(rowA0 + prow) * K + cg * 8;
    const _Float16* bStage = B + (size_t)(rowB0 + prow) * K + cg * 8;

    f32x4 acc[8][4];
#pragma unroll
    for (int i = 0; i < 8; ++i)
#pragma unroll
        for (int j = 0; j < 4; ++j) acc[i][j] = (f32x4){0.f, 0.f, 0.f, 0.f};

    f16x8 afr[2][4], bfr[2][4];

    // ---- prologue: tile0 -> slot0, tile1 -> slot1 (16 loads/thread) ----
    STAGE_A(0, 0); STAGE_A(0, 1); STAGE_B(0, 0); STAGE_B(0, 1);
    aStage += 64; bStage += 64;
    STAGE_A(1, 0); STAGE_A(1, 1); STAGE_B(1, 0); STAGE_B(1, 1);
    aStage += 64; bStage += 64;          // A,B now point at tile 2
    asm volatile("s_waitcnt vmcnt(8)" ::: "memory");   // tile0 landed
    SBAR();

    for (int j = 0; j < NITER; ++j) {
        const bool last = (j == NITER - 1);

        // ---- phase 1: tile 2j (slot0), quadrant (m0,n0) ----
        READ_A(0, 0); READ_B(0, 0);
        if (j > 0) STAGE_A(1, 0);                      // tile 2j+1 -> slot1
        SBAR();
        MFMA16(0, 0);
        SBAR();
        // ---- phase 2: (m0,n1) ----
        READ_B(0, 1);
        if (j > 0) { STAGE_A(1, 1); aStage += 64; }
        SBAR();
        MFMA16(0, 1);
        SBAR();
        // ---- phase 3: (m1,n0) ----
        READ_A(0, 1);
        if (!last) STAGE_B(0, 0);                      // tile 2j+2 -> slot0
        SBAR();
        MFMA16(1, 0);
        SBAR();
        // ---- phase 4: (m1,n1) + counted vmcnt ----
        if (!last) {
            STAGE_B(0, 1); bStage += 64;
            asm volatile("s_waitcnt vmcnt(4)" ::: "memory");
        } else {
            asm volatile("s_waitcnt vmcnt(0)" ::: "memory");
        }
        SBAR();
        MFMA16(1, 1);
        SBAR();
        // ---- phase 5: tile 2j+1 (slot1), (m0,n0) ----
        READ_A(1, 0); READ_B(1, 0);
        if (!last) STAGE_A(0, 0);                      // tile 2j+2 -> slot0
        SBAR();
        MFMA16(0, 0);
        SBAR();
        // ---- phase 6: (m0,n1) ----
        READ_B(1, 1);
        if (!last) { STAGE_A(0, 1); aStage += 64; }
        SBAR();
        MFMA16(0, 1);
        SBAR();
        // ---- phase 7: (m1,n0) ----
        READ_A(1, 1);
        if (!last) STAGE_B(1, 0);                      // tile 2j+3 -> slot1
        SBAR();
        MFMA16(1, 0);
        SBAR();
        // ---- phase 8: (m1,n1) + counted vmcnt ----
        if (!last) {
            STAGE_B(1, 1); bStage += 64;
            asm volatile("s_waitcnt vmcnt(4)" ::: "memory");
        }
        SBAR();
        MFMA16(1, 1);
        SBAR();
    }

    // ---- epilogue ----
    int gr0 = rowA0 + wr * 128;
    int gc0 = rowB0 + wc * 64;
    float ecol[4];
#pragma unroll
    for (int ni = 0; ni < 4; ++ni)
        ecol[ni] = (MODE == 0) ? e1[gc0 + ni * 16 + lrow]
                               : e0[gc0 + ni * 16 + lrow];
#pragma unroll
    for (int mi = 0; mi < 8; ++mi) {
#pragma unroll
        for (int jj = 0; jj < 4; ++jj) {
            int row = gr0 + mi * 16 + kq * 4 + jj;
            float xr = (MODE == 0) ? e0[row] : 0.f;
            size_t base = (size_t)row * 1024 + gc0 + lrow;
#pragma unroll
            for (int ni = 0; ni < 4; ++ni) {
                float v = acc[mi][ni][jj];
                if (MODE == 0) {
                    v = __expf(-GAMMA_F * (xr + ecol[ni] - 2.f * v));
                } else {
                    v += ecol[ni];
                    v = fmaxf(v, 0.f);
                }
                C[base + (size_t)ni * 16] = (_Float16)v;
            }
        }
    }
}

// ---------------------------------------------------------------------------
// head: out[b][o] = sum_s h2[b][s]*Wh[o][s] + bh[o], o in {0,1}
// ---------------------------------------------------------------------------
__global__ __launch_bounds__(256) void head_kernel(
    const _Float16* __restrict__ h2, const float* __restrict__ Wh,
    const float* __restrict__ bh, float* __restrict__ out)
{
    int lane = threadIdx.x & 63, w = threadIdx.x >> 6;
    int row = blockIdx.x * 4 + w;
    const _Float16* hp = h2 + (size_t)row * 1024;
    float s0 = 0.f, s1 = 0.f;
#pragma unroll
    for (int i = 0; i < 2; ++i) {
        int base = (i * 64 + lane) * 8;
        f16x8 hv = *(const f16x8*)(hp + base);
#pragma unroll
        for (int j = 0; j < 8; ++j) {
            float hj = (float)hv[j];
            s0 = fmaf(hj, Wh[base + j], s0);
            s1 = fmaf(hj, Wh[1024 + base + j], s1);
        }
    }
#pragma unroll
    for (int off = 32; off; off >>= 1) {
        s0 += __shfl_down(s0, off);
        s1 += __shfl_down(s1, off);
    }
    if (lane == 0) {
        out[(size_t)row * 2 + 0] = s0 + bh[0];
        out[(size_t)row * 2 + 1] = s1 + bh[1];
    }
}

// ---------------------------------------------------------------------------
extern "C" void kernel_launch(void* const* d_in, const int* in_sizes, int n_in,
                              void* d_out, int out_size, void* d_ws, size_t ws_size,
                              hipStream_t stream)
{
    const float* x  = (const float*)d_in[0];
    const float* sv = (const float*)d_in[1];
    const float* W1 = (const float*)d_in[2];
    const float* b1 = (const float*)d_in[3];
    const float* W2 = (const float*)d_in[4];
    const float* b2 = (const float*)d_in[5];
    const float* Wh = (const float*)d_in[6];
    const float* bh = (const float*)d_in[7];
    float* out = (float*)d_out;
    char* ws = (char*)d_ws;

    // ---- persistent region (~4.6 MB) ----
    constexpr size_t OFF_SV = 0;
    constexpr size_t OFF_W1 = OFF_SV + 524288;
    constexpr size_t OFF_W2 = OFF_W1 + 2097152;
    constexpr size_t OFF_S2 = OFF_W2 + 2097152;
    constexpr size_t PERSIST = OFF_S2 + 4096;

    _Float16* svf = (_Float16*)(ws + OFF_SV);
    _Float16* w1f = (_Float16*)(ws + OFF_W1);
    _Float16* w2f = (_Float16*)(ws + OFF_W2);
    float*    s2v = (float*)(ws + OFF_S2);

    // ---- adaptive batch chunking ----
    int Bc = 65536;
    while (Bc > 256 && PERSIST + (size_t)Bc * 4100ULL > ws_size) Bc >>= 1;

    char* chunk_base = ws + PERSIST;
    _Float16* kb  = (_Float16*)chunk_base;                        // Bc x 1024 fp16
    _Float16* h1b = (_Float16*)(chunk_base + (size_t)Bc * 2048);  // Bc x 1024 fp16
    _Float16* xf  = h1b;                                          // overlapped (dies before h1 written)
    float*    x2v = (float*)(chunk_base + (size_t)Bc * 4096);

    prep_rows_kernel<<<1024 / 4, 256, 0, stream>>>(sv, svf, s2v, 1024);
    cvt_kernel<<<1024, 256, 0, stream>>>(W1, w1f, 262144);
    cvt_kernel<<<1024, 256, 0, stream>>>(W2, w2f, 262144);

    int nchunks = 65536 / Bc;
    int ggrid   = (Bc / 256) * 4;
    for (int c = 0; c < nchunks; ++c) {
        const float* xc = x + (size_t)c * Bc * 256;
        prep_rows_kernel<<<Bc / 4, 256, 0, stream>>>(xc, xf, x2v, Bc);
        gemm256_kernel<0, 256><<<ggrid, 512, 0, stream>>>(xf, svf, kb, x2v, s2v);
        gemm256_kernel<1, 1024><<<ggrid, 512, 0, stream>>>(kb, w1f, h1b, b1, nullptr);
        gemm256_kernel<1, 1024><<<ggrid, 512, 0, stream>>>(h1b, w2f, kb, b2, nullptr);
        head_kernel<<<Bc / 4, 256, 0, stream>>>(kb, Wh, bh, out + (size_t)c * Bc * 2);
    }
}